// Round 12
// baseline (272.626 us; speedup 1.0000x reference)
//
#include <hip/hip_runtime.h>

// Capsule routing, factorized, multi-kernel. gemm1 = split-bf16 (hi/lo) 3-pass MFMA
// for ~fp32 accuracy at MFMA rate; squash/gemm2 fp32 VALU (R9-proven).
// B=256, K_IN=8, C=1152, J=10, D=16, 4 iters.
// m = k*1152 + c (M=9216), n = j*16 + d (N=160).

#define C_IN  1152
#define J_U   10
#define M_DIM 9216
#define N_DIM 160
#define B_SZ  256

typedef __attribute__((ext_vector_type(8))) short bf16x8;   // 8 bf16 (4 VGPRs)
typedef __attribute__((ext_vector_type(4))) float f32x4;

// ---- ws layout (float offsets), gap-checked (sizes in float-equivalents):
// xh : 256*9216 us = 1,179,648 fl  [0,         1,179,648)
// xl : 1,179,648 fl                [1,200,000, 2,379,648)
// wth:  160*9216 us =   737,280 fl [2,400,000, 3,137,280)
// wtl:    737,280 fl               [3,200,000, 3,937,280)
// Wr : 9216*160  fl = 1,474,560   [4,000,000, 5,474,560)
// sp : 144*256*160 = 5,898,240    [5,500,000, 11,398,240)
// v  : 40,960                     [11,400,000, 11,440,960)
// b0/b1: 11,520 each              [11,450,000) / [11,470,000)
// agg: 32*11,520 = 368,640        [11,500,000, 11,868,640)  => 47.5 MB total
#define OFF_XH  0
#define OFF_XL  1200000
#define OFF_WTH 2400000
#define OFF_WTL 3200000
#define OFF_WR  4000000
#define OFF_SP  5500000
#define OFF_V   11400000
#define OFF_B0  11450000
#define OFF_B1  11470000
#define OFF_AG  11500000

__device__ __forceinline__ float bf2f(unsigned short u) {
    union { unsigned int i; float f; } v; v.i = ((unsigned int)u) << 16; return v.f;
}
__device__ __forceinline__ unsigned short f2bf(float f) {
    union { float f; unsigned int i; } v; v.f = f;
    return (unsigned short)((v.i + 0x7fffu + ((v.i >> 16) & 1u)) >> 16);
}

// ================= prep: x hi/lo, Wr, W^T hi/lo =================
__global__ __launch_bounds__(256) void k_prep(const float* __restrict__ x,
                                              const float* __restrict__ W,
                                              float* __restrict__ ws) {
    __shared__ float T[64 * 161];
    const int bid = blockIdx.x, t = threadIdx.x;
    if (bid < 1152) {                      // split x into bf16 hi + lo
        unsigned short* xh = (unsigned short*)(ws + OFF_XH);
        unsigned short* xl = (unsigned short*)(ws + OFF_XL);
#pragma unroll
        for (int g = 0; g < 2; ++g) {
            const int i = bid * 512 + g * 256 + t;        // float4 index, < 589824
            const float4 v = *reinterpret_cast<const float4*>(x + (size_t)i * 4);
            const float vv[4] = {v.x, v.y, v.z, v.w};
            unsigned short h[4], l[4];
#pragma unroll
            for (int e = 0; e < 4; ++e) {
                h[e] = f2bf(vv[e]);
                l[e] = f2bf(vv[e] - bf2f(h[e]));
            }
            *reinterpret_cast<ushort2*>(xh + (size_t)i * 4)     = make_ushort2(h[0], h[1]);
            *reinterpret_cast<ushort2*>(xh + (size_t)i * 4 + 2) = make_ushort2(h[2], h[3]);
            *reinterpret_cast<ushort2*>(xl + (size_t)i * 4)     = make_ushort2(l[0], l[1]);
            *reinterpret_cast<ushort2*>(xl + (size_t)i * 4 + 2) = make_ushort2(l[2], l[3]);
        }
    } else if (bid < 2592) {               // Wr[(k*C+c)][n] = W[c][n][k]  (fp32, gemm2)
        const int i = (bid - 1152) * 256 + t;    // [0, 368640)
        const int n = i % N_DIM;
        const int c = (i / N_DIM) % C_IN;
        const int kh = i / (N_DIM * C_IN);       // 0..1
        const float4 w = *reinterpret_cast<const float4*>(W + (size_t)c * 1280 + n * 8 + kh * 4);
        float* Wr = ws + OFF_WR;
        const float wv[4] = {w.x, w.y, w.z, w.w};
#pragma unroll
        for (int j = 0; j < 4; ++j)
            Wr[(size_t)((kh * 4 + j) * C_IN + c) * N_DIM + n] = wv[j];
    } else {                               // Wt{h,l}[n][k*1152+c] = split(W[c][n][k])
        const int bc = bid - 2592;               // 144 = 8 k x 18 c-tiles
        const int k = bc / 18, c0 = (bc % 18) * 64;
        for (int i = t; i < 10240; i += 256) {
            const int c = i / 160, n = i - c * 160;
            T[c * 161 + n] = W[(size_t)(c0 + c) * 1280 + n * 8 + k];
        }
        __syncthreads();
        unsigned short* wth = (unsigned short*)(ws + OFF_WTH);
        unsigned short* wtl = (unsigned short*)(ws + OFF_WTL);
        for (int i = t; i < 10240; i += 256) {
            const int n = i >> 6, cl = i & 63;
            const float f = T[cl * 161 + n];
            const unsigned short h = f2bf(f);
            wth[(size_t)n * M_DIM + k * C_IN + c0 + cl] = h;
            wtl[(size_t)n * M_DIM + k * C_IN + c0 + cl] = f2bf(f - bf2f(h));
        }
    }
}

// ================= gemm1 (split-bf16 MFMA): 144 chunks(64 m) x 4 bq = 576 blocks ====
__global__ __launch_bounds__(256, 2) void k_gemm1(const unsigned short* __restrict__ xh,
                                                  const unsigned short* __restrict__ xl,
                                                  const unsigned short* __restrict__ wth,
                                                  const unsigned short* __restrict__ wtl,
                                                  const float* __restrict__ bij_old,
                                                  float* __restrict__ bij_new,
                                                  const float* __restrict__ agg_part,
                                                  float* __restrict__ s_part,
                                                  int first) {
    __shared__ float braw[640];
    __shared__ float csm[640];                            // [64 c][10 j]
    __shared__ alignas(16) unsigned short Xh[64 * 72];    // [64 b][64 k +8 pad]
    __shared__ alignas(16) unsigned short Xl[64 * 72];
    __shared__ alignas(16) unsigned short Wh[160 * 72];   // [160 n][64 k +8 pad]
    __shared__ alignas(16) unsigned short Wl[160 * 72];
    const int ch = blockIdx.x >> 2, bq = blockIdx.x & 3;
    const int m0 = ch * 64;
    const int c0 = (ch % 18) * 64;             // 64-m chunk sits inside one k-slice
    const int b0 = bq * 64;
    const int t = threadIdx.x;

    if (first) {
        for (int i = t; i < 640; i += 256) { csm[i] = 0.1f; bij_new[c0 * J_U + i] = 0.f; }
    } else {
        for (int i = t; i < 640; i += 256) {
            float v = bij_old[c0 * J_U + i];
#pragma unroll
            for (int s = 0; s < 32; ++s) v += agg_part[s * 11520 + c0 * J_U + i];
            braw[i] = v;
            bij_new[c0 * J_U + i] = v;
        }
        __syncthreads();
        for (int i = t; i < 640; i += 256) {
            const int r0 = (i / J_U) * J_U;
            float mx = -1e30f;
#pragma unroll
            for (int j = 0; j < J_U; ++j) mx = fmaxf(mx, braw[r0 + j]);
            float sum = 0.f;
#pragma unroll
            for (int j = 0; j < J_U; ++j) sum += __expf(braw[r0 + j] - mx);
            csm[i] = __expf(braw[i] - mx) / sum;
        }
    }
    __syncthreads();
    // ---- stage X hi/lo (coalesced, 64 B/thread) ----
    {
        const int row = t >> 2, q = t & 3;
        const size_t off = (size_t)(b0 + row) * M_DIM + m0 + q * 16;
        const uint4* sh = reinterpret_cast<const uint4*>(xh + off);
        const uint4* sl = reinterpret_cast<const uint4*>(xl + off);
        const uint4 h0 = sh[0], h1 = sh[1], l0 = sl[0], l1 = sl[1];
        *reinterpret_cast<uint4*>(&Xh[row * 72 + q * 16])     = h0;
        *reinterpret_cast<uint4*>(&Xh[row * 72 + q * 16 + 8]) = h1;
        *reinterpret_cast<uint4*>(&Xl[row * 72 + q * 16])     = l0;
        *reinterpret_cast<uint4*>(&Xl[row * 72 + q * 16 + 8]) = l1;
    }
    // ---- stage W: reconstruct fp32, scale by csm, split hi/lo ----
    for (int i = t; i < 640; i += 256) {     // 160 rows x 4 k-quarters (16 elems)
        const int n = i >> 2, q = i & 3;
        const int j = n >> 4;
        const size_t off = (size_t)n * M_DIM + m0 + q * 16;
        union { uint4 v; unsigned short s[8]; } ha, hb, la, lb, oh0, oh1, ol0, ol1;
        ha.v = *reinterpret_cast<const uint4*>(wth + off);
        hb.v = *reinterpret_cast<const uint4*>(wth + off + 8);
        la.v = *reinterpret_cast<const uint4*>(wtl + off);
        lb.v = *reinterpret_cast<const uint4*>(wtl + off + 8);
#pragma unroll
        for (int e = 0; e < 8; ++e) {
            const float w0 = (bf2f(ha.s[e]) + bf2f(la.s[e])) * csm[(q * 16 + e) * J_U + j];
            const unsigned short h0 = f2bf(w0);
            oh0.s[e] = h0;
            ol0.s[e] = f2bf(w0 - bf2f(h0));
            const float w1 = (bf2f(hb.s[e]) + bf2f(lb.s[e])) * csm[(q * 16 + 8 + e) * J_U + j];
            const unsigned short h1 = f2bf(w1);
            oh1.s[e] = h1;
            ol1.s[e] = f2bf(w1 - bf2f(h1));
        }
        *reinterpret_cast<uint4*>(&Wh[n * 72 + q * 16])     = oh0.v;
        *reinterpret_cast<uint4*>(&Wh[n * 72 + q * 16 + 8]) = oh1.v;
        *reinterpret_cast<uint4*>(&Wl[n * 72 + q * 16])     = ol0.v;
        *reinterpret_cast<uint4*>(&Wl[n * 72 + q * 16 + 8]) = ol1.v;
    }
    __syncthreads();
    // ---- MFMA main: 2 k-steps x 10 n-tiles x 3 passes (hh, lh, hl) ----
    const int w = t >> 6, l = t & 63;
    const int lm = l & 15, lq = l >> 4;
    f32x4 acc[10];
#pragma unroll
    for (int j = 0; j < 10; ++j) acc[j] = (f32x4){0.f, 0.f, 0.f, 0.f};
#pragma unroll
    for (int ks = 0; ks < 2; ++ks) {
        const int aoff = (w * 16 + lm) * 72 + ks * 32 + lq * 8;
        const bf16x8 ah = *reinterpret_cast<const bf16x8*>(&Xh[aoff]);
        const bf16x8 al = *reinterpret_cast<const bf16x8*>(&Xl[aoff]);
#pragma unroll
        for (int j = 0; j < 10; ++j) {
            const int boff = (j * 16 + lm) * 72 + ks * 32 + lq * 8;
            const bf16x8 bh = *reinterpret_cast<const bf16x8*>(&Wh[boff]);
            const bf16x8 bl = *reinterpret_cast<const bf16x8*>(&Wl[boff]);
            acc[j] = __builtin_amdgcn_mfma_f32_16x16x32_bf16(ah, bh, acc[j], 0, 0, 0);
            acc[j] = __builtin_amdgcn_mfma_f32_16x16x32_bf16(al, bh, acc[j], 0, 0, 0);
            acc[j] = __builtin_amdgcn_mfma_f32_16x16x32_bf16(ah, bl, acc[j], 0, 0, 0);
        }
    }
    // ---- epilogue: C/D layout col=lane&15, row=lq*4+reg ----
    float* sp = s_part + (size_t)ch * 40960 + (size_t)b0 * N_DIM;
#pragma unroll
    for (int j = 0; j < 10; ++j)
#pragma unroll
        for (int r = 0; r < 4; ++r)
            sp[(size_t)(w * 16 + lq * 4 + r) * N_DIM + j * 16 + lm] = acc[j][r];
}

// ================= squash: reduce 144 slices, squash over d -> dst =================
__global__ __launch_bounds__(320) void k_squash(const float* __restrict__ s_part,
                                                float* __restrict__ dst) {
    __shared__ float red[320];
    __shared__ float sq[160];
    const int b = blockIdx.x, t = threadIdx.x;
    const int n = t % 160, h = t / 160;
    float s = 0.f;
    const float* p = s_part + (size_t)h * 72 * 40960 + (size_t)b * N_DIM + n;
#pragma unroll 8
    for (int sl = 0; sl < 72; ++sl) s += p[(size_t)sl * 40960];
    red[t] = s;
    __syncthreads();
    if (t < 160) {
        s = red[t] + red[t + 160] + 1e-5f;   // reference adds 1e-5 BEFORE magnitudes
        sq[t] = s * s;
        red[t] = s;
    }
    __syncthreads();
    if (t < 160) {
        const int j0 = t & ~15;
        float mag = 0.f;
#pragma unroll
        for (int d = 0; d < 16; ++d) mag += sq[j0 + d];
        dst[(size_t)b * N_DIM + t] = red[t] * (sqrtf(mag) / (1.f + mag));
    }
}

// ================= gemm2: 144 m-tiles(64) x 4 b-quarters(64 b) = 576 blocks =========
__global__ __launch_bounds__(256) void k_gemm2(const float* __restrict__ x,
                                               const float* __restrict__ v,
                                               const float* __restrict__ Wr,
                                               float* __restrict__ agg_part) {
    __shared__ alignas(16) float VG[64 * 164];   // v-panel [64][160] then G-tile [64][164]
    __shared__ float agg[640];                   // 64 c x 10 j
    const int mt = blockIdx.x >> 2, bq = blockIdx.x & 3;
    const int m0 = mt * 64, b0 = bq * 64;
    const int t = threadIdx.x;
    const int tm = t & 15, ng = t >> 4;

    float4* Vs4 = reinterpret_cast<float4*>(VG);
    const float4* v4 = reinterpret_cast<const float4*>(v);
    for (int i = t; i < 2560; i += 256) Vs4[i] = v4[(size_t)bq * 2560 + i];
    for (int i = t; i < 640; i += 256) agg[i] = 0.f;
    __syncthreads();

    float acc[4][10] = {};
    const float* xb = x + (size_t)b0 * M_DIM + m0 + tm * 4;
    const float2* Vs2 = reinterpret_cast<const float2*>(VG);
    float4 pf[4];
#pragma unroll
    for (int i = 0; i < 4; ++i) pf[i] = *reinterpret_cast<const float4*>(xb + (size_t)i * M_DIM);
#pragma unroll 4
    for (int b = 0; b < 64; ++b) {
        const int bf = (b + 4 < 64) ? b + 4 : 63;            // clamped prefetch
        const float4 nxt = *reinterpret_cast<const float4*>(xb + (size_t)bf * M_DIM);
        const float4 cur = pf[0];
        pf[0] = pf[1]; pf[1] = pf[2]; pf[2] = pf[3]; pf[3] = nxt;
        const float2* vv = Vs2 + b * 80 + ng * 5;
        const float xv[4] = {cur.x, cur.y, cur.z, cur.w};
#pragma unroll
        for (int jj = 0; jj < 5; ++jj) {
            const float2 w = vv[jj];
#pragma unroll
            for (int i = 0; i < 4; ++i) {
                acc[i][2 * jj]     += xv[i] * w.x;
                acc[i][2 * jj + 1] += xv[i] * w.y;
            }
        }
    }
    __syncthreads();
#pragma unroll
    for (int i = 0; i < 4; ++i)
#pragma unroll
        for (int q = 0; q < 10; ++q)
            VG[(tm * 4 + i) * 164 + ng * 10 + q] = acc[i][q];
    __syncthreads();
    const float4* Wr4 = reinterpret_cast<const float4*>(Wr);
    for (int idx = t; idx < 2560; idx += 256) {
        const int row = idx / 40, q = idx - row * 40;
        const float4 w = Wr4[(size_t)(m0 + row) * 40 + q];
        const float4 g = *reinterpret_cast<const float4*>(&VG[row * 164 + q * 4]);
        atomicAdd(&agg[row * J_U + (q >> 2)], w.x * g.x + w.y * g.y + w.z * g.z + w.w * g.w);
    }
    __syncthreads();
    const int k = m0 / C_IN, c0 = m0 - k * C_IN;
    for (int i = t; i < 640; i += 256)
        agg_part[(size_t)(bq * 8 + k) * 11520 + c0 * J_U + i] = agg[i];
}

extern "C" void kernel_launch(void* const* d_in, const int* in_sizes, int n_in,
                              void* d_out, int out_size, void* d_ws, size_t ws_size,
                              hipStream_t stream) {
    const float* x = (const float*)d_in[0];   // (256, 8, 1152) fp32
    const float* W = (const float*)d_in[1];   // (1, 1152, 10, 16, 8) fp32
    float* out = (float*)d_out;               // (256, 10, 16, 1) fp32
    float* ws  = (float*)d_ws;
    const unsigned short* xh  = (const unsigned short*)(ws + OFF_XH);
    const unsigned short* xl  = (const unsigned short*)(ws + OFF_XL);
    const unsigned short* wth = (const unsigned short*)(ws + OFF_WTH);
    const unsigned short* wtl = (const unsigned short*)(ws + OFF_WTL);
    float* Wr   = ws + OFF_WR;
    float* sp   = ws + OFF_SP;
    float* v    = ws + OFF_V;
    float* bij0 = ws + OFF_B0;
    float* bij1 = ws + OFF_B1;
    float* agg  = ws + OFF_AG;

    k_prep<<<2736, 256, 0, stream>>>(x, W, ws);

    for (int it = 0; it < 4; ++it) {
        const float* bo = (it & 1) ? bij1 : bij0;
        float*       bn = (it & 1) ? bij0 : bij1;
        k_gemm1<<<576, 256, 0, stream>>>(xh, xl, wth, wtl, bo, bn, agg, sp, it == 0 ? 1 : 0);
        k_squash<<<256, 320, 0, stream>>>(sp, (it < 3) ? v : out);
        if (it < 3)   // last iteration's agreement is never used
            k_gemm2<<<576, 256, 0, stream>>>(x, v, Wr, agg);
    }
}